// Round 7
// baseline (195.446 us; speedup 1.0000x reference)
//
#include <hip/hip_runtime.h>
#include <hip/hip_bf16.h>

#define BATCH 8
#define SEQ   512
#define DIM   512
#define NL    64

typedef float f32x4 __attribute__((ext_vector_type(4)));

// proj v2 — byte-identical to rounds 5/6. Launched 3x this round as a
// decomposition probe (pure function of inputs -> idempotent, deterministic).
__global__ __launch_bounds__(256) void alab_proj2(
    const float* __restrict__ head, const float* __restrict__ dep,
    const float* __restrict__ W, const float* __restrict__ bias,
    float* __restrict__ hbuf, float* __restrict__ dbuf)
{
    __shared__ float4 srow[16][129];            // 16 x 512 f32, +16B row pad
    const int bid   = blockIdx.x;
    const int hd    = bid & 1;                  // 0 = head->h, 1 = dep->d
    const int itile = (bid >> 1) & 31;
    const int b     = bid >> 6;
    const int i0    = itile * 16;

    const float* src  = hd ? dep  : head;
    float*       dst  = hd ? dbuf : hbuf;
    const int    wofs = hd ? 128  : 0;          // float4 offset into W row

    const float4* s4 = (const float4*)(src + ((size_t)b * SEQ + i0) * DIM);
    #pragma unroll
    for (int u = threadIdx.x; u < 16 * 128; u += 256)
        srow[u >> 7][u & 127] = s4[u];
    __syncthreads();

    const int lane = threadIdx.x & 63;
    const int w    = threadIdx.x >> 6;          // 0..3
    const int i    = lane & 15;
    const int li   = lane >> 4;                 // 0..3
    const int lb   = w * 16 + li * 4;           // l = lb + s

    const f32x4* W4 = (const f32x4*)W;          // [NL][256] f32x4
    f32x4 a0 = {0.f,0.f,0.f,0.f}, a1 = {0.f,0.f,0.f,0.f};
    f32x4 a2 = {0.f,0.f,0.f,0.f}, a3 = {0.f,0.f,0.f,0.f};

    #pragma unroll 4
    for (int k4 = 0; k4 < 128; ++k4) {
        const f32x4 hv = *(const f32x4*)&srow[i][k4];
        const size_t wb = (size_t)lb * 256 + wofs + k4;
        a0 += hv * W4[wb];
        a1 += hv * W4[wb + 256];
        a2 += hv * W4[wb + 512];
        a3 += hv * W4[wb + 768];
    }

    float r[4] = { a0.x + a0.y + a0.z + a0.w,
                   a1.x + a1.y + a1.z + a1.w,
                   a2.x + a2.y + a2.z + a2.w,
                   a3.x + a3.y + a3.z + a3.w };
    #pragma unroll
    for (int s = 0; s < 4; ++s) {
        const int l = lb + s;
        const float v = r[s] + (hd ? 0.f : bias[l]);   // bias folded into h
        dst[((size_t)b * NL + l) * SEQ + i0 + i] = v;
    }
}

// bcast v4 — byte-identical to round 6.
__global__ __launch_bounds__(256) void alab_bcast4(
    const float* __restrict__ hbuf, const float* __restrict__ dbuf,
    float* __restrict__ out)
{
    __shared__ float sh[SEQ];        // full h row for this (b,l)
    __shared__ f32x4 sd4[SEQ / 4];   // full d row
    const int t  = threadIdx.x;
    const int bl = blockIdx.x;       // b*NL + l, 0..511

    sh[t]                  = hbuf[(size_t)bl * SEQ + t];
    sh[t + 256]            = hbuf[(size_t)bl * SEQ + t + 256];
    ((float*)sd4)[t]       = dbuf[(size_t)bl * SEQ + t];
    ((float*)sd4)[t + 256] = dbuf[(size_t)bl * SEQ + t + 256];
    __syncthreads();

    const int j4 = t & 127;                     // fixed float4 column
    const int rh = t >> 7;                      // row parity (0/1)
    const f32x4 dreg = sd4[j4];                 // loop-invariant
    f32x4* ob = (f32x4*)out + (size_t)bl * SEQ * (SEQ / 4);

    #pragma unroll 8
    for (int ii = 0; ii < SEQ; ii += 2) {
        const int i = ii + rh;
        ob[(size_t)i * (SEQ / 4) + j4] = dreg + sh[i];
    }
}

extern "C" void kernel_launch(void* const* d_in, const int* in_sizes, int n_in,
                              void* d_out, int out_size, void* d_ws, size_t ws_size,
                              hipStream_t stream) {
    const float* head = (const float*)d_in[0];
    const float* dep  = (const float*)d_in[1];
    const float* W    = (const float*)d_in[2];
    const float* bias = (const float*)d_in[3];
    float* out  = (float*)d_out;
    float* hbuf = (float*)d_ws;                          // 1 MiB
    float* dbuf = hbuf + (size_t)BATCH * NL * SEQ;       // 1 MiB

    // DECOMPOSITION PROBE: proj2 launched 3x (idempotent). Extra total time
    // vs round 6 = 2 x proj2 duration.
    alab_proj2<<<BATCH * 32 * 2, 256, 0, stream>>>(head, dep, W, bias, hbuf, dbuf);
    alab_proj2<<<BATCH * 32 * 2, 256, 0, stream>>>(head, dep, W, bias, hbuf, dbuf);
    alab_proj2<<<BATCH * 32 * 2, 256, 0, stream>>>(head, dep, W, bias, hbuf, dbuf);
    alab_bcast4<<<BATCH * NL, 256, 0, stream>>>(hbuf, dbuf, out);
}

// Round 8
// 133.296 us; speedup vs baseline: 1.4663x; 1.4663x over previous
//
#include <hip/hip_runtime.h>
#include <hip/hip_bf16.h>

#define BATCH 8
#define SEQ   512
#define DIM   512
#define NL    64

typedef float f32x4 __attribute__((ext_vector_type(4)));

// proj v3: k-split x2. Block = (b, itile16, hd, ks). Grid = 8*32*2*2 = 2048
// -> 8 blocks/CU (LDS 16.6 KB allows 9), 4 waves/SIMD for latency hiding.
// Each block stages its 16-row x k-half tile (16 KB) and computes partial
// dots over 64 k4's into hbuf_ks / dbuf_ks. bcast sums the two partials.
__global__ __launch_bounds__(256) void alab_proj3(
    const float* __restrict__ head, const float* __restrict__ dep,
    const float* __restrict__ W, const float* __restrict__ bias,
    float* __restrict__ ws)
{
    __shared__ float4 srow[16][65];             // 16 rows x 64 f32x4, +16B pad
    const int bid   = blockIdx.x;
    const int ks    = bid & 1;                  // k half
    const int hd    = (bid >> 1) & 1;           // 0 = head->h, 1 = dep->d
    const int itile = (bid >> 2) & 31;
    const int b     = bid >> 7;
    const int i0    = itile * 16;

    const float* src = hd ? dep : head;
    float* dst = ws + (size_t)(hd * 2 + ks) * (BATCH * NL * SEQ);
    const int wofs = hd ? 128 : 0;              // f32x4 offset into W row

    // stage 16 rows x 64 f32x4 (this k-half), 1 KB contiguous per wave-iter
    const float4* s4 = (const float4*)(src + ((size_t)b * SEQ + i0) * DIM);
    #pragma unroll
    for (int u = threadIdx.x; u < 16 * 64; u += 256)
        srow[u >> 6][u & 63] = s4[(size_t)(u >> 6) * 128 + ks * 64 + (u & 63)];
    __syncthreads();

    const int lane = threadIdx.x & 63;
    const int w    = threadIdx.x >> 6;          // 0..3
    const int i    = lane & 15;
    const int li   = lane >> 4;                 // 0..3
    const int lb   = w * 16 + li * 4;           // l = lb + s

    const f32x4* W4 = (const f32x4*)W;          // [NL][256] f32x4
    f32x4 a0 = {0.f,0.f,0.f,0.f}, a1 = {0.f,0.f,0.f,0.f};
    f32x4 a2 = {0.f,0.f,0.f,0.f}, a3 = {0.f,0.f,0.f,0.f};

    #pragma unroll 4
    for (int k4 = 0; k4 < 64; ++k4) {
        const f32x4 hv = *(const f32x4*)&srow[i][k4];
        const size_t wb = (size_t)lb * 256 + wofs + ks * 64 + k4;
        a0 += hv * W4[wb];
        a1 += hv * W4[wb + 256];
        a2 += hv * W4[wb + 512];
        a3 += hv * W4[wb + 768];
    }

    float r[4] = { a0.x + a0.y + a0.z + a0.w,
                   a1.x + a1.y + a1.z + a1.w,
                   a2.x + a2.y + a2.z + a2.w,
                   a3.x + a3.y + a3.z + a3.w };
    #pragma unroll
    for (int s = 0; s < 4; ++s) {
        const int l = lb + s;
        // bias folded into the ks==0 h-partial
        const float v = r[s] + ((hd == 0 && ks == 0) ? bias[l] : 0.f);
        dst[((size_t)b * NL + l) * SEQ + i0 + i] = v;
    }
}

// bcast v4b: identical store loop to round 6; preamble now sums the two
// k-split partials during the LDS preload.
__global__ __launch_bounds__(256) void alab_bcast4b(
    const float* __restrict__ ws, float* __restrict__ out)
{
    __shared__ float sh[SEQ];        // full h row for this (b,l)
    __shared__ f32x4 sd4[SEQ / 4];   // full d row
    const int t  = threadIdx.x;
    const int bl = blockIdx.x;       // b*NL + l, 0..511
    const size_t P = (size_t)BATCH * NL * SEQ;
    const float* h0 = ws;
    const float* h1 = ws + P;
    const float* d0 = ws + 2 * P;
    const float* d1 = ws + 3 * P;
    const size_t base = (size_t)bl * SEQ;

    sh[t]                  = h0[base + t]       + h1[base + t];
    sh[t + 256]            = h0[base + t + 256] + h1[base + t + 256];
    ((float*)sd4)[t]       = d0[base + t]       + d1[base + t];
    ((float*)sd4)[t + 256] = d0[base + t + 256] + d1[base + t + 256];
    __syncthreads();

    const int j4 = t & 127;                     // fixed float4 column
    const int rh = t >> 7;                      // row parity (0/1)
    const f32x4 dreg = sd4[j4];                 // loop-invariant
    f32x4* ob = (f32x4*)out + (size_t)bl * SEQ * (SEQ / 4);

    #pragma unroll 8
    for (int ii = 0; ii < SEQ; ii += 2) {
        const int i = ii + rh;
        ob[(size_t)i * (SEQ / 4) + j4] = dreg + sh[i];
    }
}

extern "C" void kernel_launch(void* const* d_in, const int* in_sizes, int n_in,
                              void* d_out, int out_size, void* d_ws, size_t ws_size,
                              hipStream_t stream) {
    const float* head = (const float*)d_in[0];
    const float* dep  = (const float*)d_in[1];
    const float* W    = (const float*)d_in[2];
    const float* bias = (const float*)d_in[3];
    float* out = (float*)d_out;
    float* ws  = (float*)d_ws;                   // 4 x 1 MiB partial buffers

    alab_proj3<<<BATCH * 32 * 2 * 2, 256, 0, stream>>>(head, dep, W, bias, ws);
    alab_bcast4b<<<BATCH * NL, 256, 0, stream>>>(ws, out);
}

// Round 9
// 119.647 us; speedup vs baseline: 1.6335x; 1.1141x over previous
//
#include <hip/hip_runtime.h>
#include <hip/hip_bf16.h>

#define BATCH 8
#define SEQ   512
#define DIM   512
#define NL    64

typedef float f32x4 __attribute__((ext_vector_type(4)));

// Kernel 0: transpose W[64][1024] -> WT4[hd][k4][l], where WT4 element
// (hd,k4,l) = f32x4 of W[l][hd*512 + 4*k4 .. +3]. 256 KB, one-time.
// Reads are 16B-scattered (64 lines/wave), writes fully coalesced; tiny.
__global__ __launch_bounds__(256) void alab_wt(
    const float* __restrict__ W, f32x4* __restrict__ wt4)
{
    const int tid = blockIdx.x * 256 + threadIdx.x;   // 0..16383
    const int l   = tid & 63;
    const int k4  = (tid >> 6) & 127;
    const int hd  = tid >> 13;
    wt4[tid] = *(const f32x4*)(W + (size_t)l * (2 * DIM) + hd * DIM + k4 * 4);
}

// Kernel 1 (proj v4): lane = l. Per k4-iteration: ONE coalesced 1KB VMEM
// load of WT4 (64 lanes x 16B contiguous) + 4 uniform LDS broadcasts of the
// staged input row + 16 FMA. 262K total VMEM instrs vs 2M in v2/v3 (which
// were TA-throughput-bound at 64 useful B/instr -> ~31 us, insensitive to
// occupancy per R7/R8 evidence).
// Grid: b(8) x itile16(32) x hd(2) = 512 blocks, 256 thr = 4 waves x 4 i.
__global__ __launch_bounds__(256) void alab_proj4(
    const float* __restrict__ head, const float* __restrict__ dep,
    const f32x4* __restrict__ wt4, const float* __restrict__ bias,
    float* __restrict__ hbuf, float* __restrict__ dbuf)
{
    __shared__ f32x4 srow[16][128];             // 32 KB staged input tile
    const int bid   = blockIdx.x;
    const int hd    = bid & 1;                  // 0 = head->h, 1 = dep->d
    const int itile = (bid >> 1) & 31;
    const int b     = bid >> 6;
    const int i0    = itile * 16;

    const float* src = hd ? dep  : head;
    float*       dst = hd ? dbuf : hbuf;

    const f32x4* s4 = (const f32x4*)(src + ((size_t)b * SEQ + i0) * DIM);
    #pragma unroll
    for (int u = threadIdx.x; u < 16 * 128; u += 256)
        srow[u >> 7][u & 127] = s4[u];
    __syncthreads();

    const int lane = threadIdx.x & 63;          // = l
    const int w    = threadIdx.x >> 6;          // wave -> i = w*4 + ii

    const f32x4* wbase = wt4 + (size_t)hd * 128 * 64 + lane;
    f32x4 a0 = {0,0,0,0}, a1 = {0,0,0,0}, a2 = {0,0,0,0}, a3 = {0,0,0,0};
    #pragma unroll 4
    for (int k4 = 0; k4 < 128; ++k4) {
        const f32x4 wt = wbase[(size_t)k4 * 64];   // coalesced 1KB/wave
        a0 += srow[w * 4 + 0][k4] * wt;            // uniform addr: broadcast
        a1 += srow[w * 4 + 1][k4] * wt;
        a2 += srow[w * 4 + 2][k4] * wt;
        a3 += srow[w * 4 + 3][k4] * wt;
    }
    const float bb = hd ? 0.f : bias[lane];        // bias folded into h
    f32x4 r = { a0.x + a0.y + a0.z + a0.w + bb,
                a1.x + a1.y + a1.z + a1.w + bb,
                a2.x + a2.y + a2.z + a2.w + bb,
                a3.x + a3.y + a3.z + a3.w + bb };
    // 4 consecutive f32 per thread -> one 16B store (i0 + w*4 is 16B-aligned)
    *(f32x4*)(dst + ((size_t)b * NL + lane) * SEQ + i0 + w * 4) = r;
}

// bcast v4 — byte-identical to round 6.
__global__ __launch_bounds__(256) void alab_bcast4(
    const float* __restrict__ hbuf, const float* __restrict__ dbuf,
    float* __restrict__ out)
{
    __shared__ float sh[SEQ];        // full h row for this (b,l)
    __shared__ f32x4 sd4[SEQ / 4];   // full d row
    const int t  = threadIdx.x;
    const int bl = blockIdx.x;       // b*NL + l, 0..511

    sh[t]                  = hbuf[(size_t)bl * SEQ + t];
    sh[t + 256]            = hbuf[(size_t)bl * SEQ + t + 256];
    ((float*)sd4)[t]       = dbuf[(size_t)bl * SEQ + t];
    ((float*)sd4)[t + 256] = dbuf[(size_t)bl * SEQ + t + 256];
    __syncthreads();

    const int j4 = t & 127;                     // fixed float4 column
    const int rh = t >> 7;                      // row parity (0/1)
    const f32x4 dreg = sd4[j4];                 // loop-invariant
    f32x4* ob = (f32x4*)out + (size_t)bl * SEQ * (SEQ / 4);

    #pragma unroll 8
    for (int ii = 0; ii < SEQ; ii += 2) {
        const int i = ii + rh;
        ob[(size_t)i * (SEQ / 4) + j4] = dreg + sh[i];
    }
}

extern "C" void kernel_launch(void* const* d_in, const int* in_sizes, int n_in,
                              void* d_out, int out_size, void* d_ws, size_t ws_size,
                              hipStream_t stream) {
    const float* head = (const float*)d_in[0];
    const float* dep  = (const float*)d_in[1];
    const float* W    = (const float*)d_in[2];
    const float* bias = (const float*)d_in[3];
    float* out = (float*)d_out;

    const size_t P = (size_t)BATCH * NL * SEQ;           // 262144 floats
    float* hbuf = (float*)d_ws;                          // 1 MiB
    float* dbuf = hbuf + P;                              // 1 MiB
    f32x4* wt4  = (f32x4*)(dbuf + P);                    // 256 KB

    alab_wt   <<<64,         256, 0, stream>>>(W, wt4);
    alab_proj4<<<BATCH * 64, 256, 0, stream>>>(head, dep, wt4, bias, hbuf, dbuf);
    alab_bcast4<<<BATCH * NL, 256, 0, stream>>>(hbuf, dbuf, out);
}